// Round 16
// baseline (243.322 us; speedup 1.0000x reference)
//
#include <hip/hip_runtime.h>

typedef unsigned short u16;
typedef __attribute__((ext_vector_type(8))) short short8;    // 8 x 16-bit payload
typedef __attribute__((ext_vector_type(4))) short s16x4;
typedef __attribute__((ext_vector_type(8))) _Float16 half8;  // MFMA f16 A/B frag
typedef __attribute__((ext_vector_type(4))) float f32x4;
typedef __attribute__((ext_vector_type(16))) float f32x16;
typedef __attribute__((ext_vector_type(4))) unsigned int u32x4;

#define DEVI static __device__ __forceinline__

static constexpr int B_ = 4, N_ = 2048, C_ = 1024, H_ = 16, D_ = 64;
static constexpr int M_ = B_ * N_;   // 8192
static constexpr int C3 = 3072;      // qkv row stride (3C)

DEVI u16 f2h(float f) {
  _Float16 h = (_Float16)f;          // v_cvt_f16_f32, RTN
  return __builtin_bit_cast(u16, h);
}

DEVI unsigned pk2h(float lo, float hi) {  // pack 2 f32 -> 2 f16 (lo in [15:0])
  return __builtin_bit_cast(unsigned, __builtin_amdgcn_cvt_pkrtz(lo, hi));
}

DEVI void gload_lds16(const void* g, void* lds) {
  __builtin_amdgcn_global_load_lds(
      (const __attribute__((address_space(1))) unsigned int*)g,
      (__attribute__((address_space(3))) unsigned int*)lds, 16, 0, 0);
}

// f32 -> f16 cast, 8 elems/thread
__global__ __launch_bounds__(256) void f32_to_f16(const float* __restrict__ src,
                                                  u16* __restrict__ dst, int n8) {
  int idx = blockIdx.x * 256 + threadIdx.x;
  if (idx >= n8) return;
  const float* s = src + (size_t)idx * 8;
  f32x4 f0 = *(const f32x4*)s;
  f32x4 f1 = *(const f32x4*)(s + 4);
  short8 o;
#pragma unroll
  for (int j = 0; j < 8; ++j) o[j] = (short)f2h(j < 4 ? f0[j] : f1[j - 4]);
  *(short8*)(dst + (size_t)idx * 8) = o;
}

// C[M][Nout] = A[M][1024] * B[Nout][1024]^T + bias.
// Round 16: 256x128 tile, BK=32, 512 threads (8 waves, 2Mx4N), 3-deep LDS
// pipeline with COUNTED vmcnt (T4): tile t computed from buf[t%3] while tile
// t+2 stages into buf[(t+2)%3]; per-tile sync = s_waitcnt vmcnt(3) + raw
// s_barrier (never a vmcnt(0) drain mid-loop). Race-safe by construction:
// the buffer written was last read two barriers ago.
template <bool OUT_F16>
__global__ __launch_bounds__(512, 2) void gemm_bt(const u16* __restrict__ A,
                                                  const u16* __restrict__ Bm,
                                                  const float* __restrict__ bias,
                                                  void* __restrict__ outp, int Nout) {
  __shared__ u16 As[3][256 * 32];
  __shared__ u16 Bs[3][128 * 32];
  const int tid = threadIdx.x;
  const int w = tid >> 6, l = tid & 63;
  const int wr = w >> 2, wc = w & 3;
  const int l15 = l & 15, lg = l >> 4;
  const int nx = gridDim.x;
  int bid = blockIdx.y * nx + blockIdx.x;
  int cpx = (nx * gridDim.y) >> 3;
  int swz = (bid & 7) * cpx + (bid >> 3);
  int bx = swz % nx, by = swz / nx;
  const u16* Ab = A + (size_t)(bx * 256) * C_;
  const u16* Bb = Bm + (size_t)(by * 128) * C_;

  f32x4 acc[8][2];
#pragma unroll
  for (int m = 0; m < 8; ++m)
#pragma unroll
    for (int n = 0; n < 2; ++n) acc[m][n] = (f32x4){0.f, 0.f, 0.f, 0.f};

  // STAGE one K-tile (A 256x32, B 128x32) -> buffers bb. 3 gloads/thread.
  auto STAGE = [&](int t, int bb) {
    const int kt = t * 32;
#pragma unroll
    for (int i = 0; i < 2; ++i) {
      const int c = i * 512 + tid;                 // A chunk 0..1023
      gload_lds16(Ab + (size_t)(c >> 2) * C_ + kt + (c & 3) * 8,
                  (char*)&As[bb][0] + (i * 512 + w * 64) * 16);
    }
    gload_lds16(Bb + (size_t)(tid >> 2) * C_ + kt + (tid & 3) * 8,
                (char*)&Bs[bb][0] + (w * 64) * 16);
  };

  STAGE(0, 0);
  STAGE(1, 1);
  asm volatile("s_waitcnt vmcnt(3)" ::: "memory");   // tile 0 landed; tile 1 in flight
  __builtin_amdgcn_sched_barrier(0);
  __builtin_amdgcn_s_barrier();
  __builtin_amdgcn_sched_barrier(0);

  for (int t = 0; t < 32; ++t) {
    const int cur = t % 3;
    if (t + 2 < 32) STAGE(t + 2, (t + 2) % 3);
    const char* Ablk = (const char*)&As[cur][0];
    const char* Bblk = (const char*)&Bs[cur][0];
    half8 bf[2];
#pragma unroll
    for (int n = 0; n < 2; ++n)
      bf[n] = __builtin_bit_cast(half8, *(const short8*)(Bblk +
                  (wc * 32 + n * 16 + l15) * 64 + lg * 16));
    half8 af[8];
#pragma unroll
    for (int m = 0; m < 8; ++m)
      af[m] = __builtin_bit_cast(half8, *(const short8*)(Ablk +
                  (wr * 128 + m * 16 + l15) * 64 + lg * 16));
#pragma unroll
    for (int m = 0; m < 8; ++m)
#pragma unroll
      for (int n = 0; n < 2; ++n)
        acc[m][n] = __builtin_amdgcn_mfma_f32_16x16x32_f16(af[m], bf[n], acc[m][n], 0, 0, 0);
    if (t + 1 < 32) {
      if (t + 2 < 32)
        asm volatile("s_waitcnt vmcnt(3)" ::: "memory");  // t+1 landed; t+2 in flight
      else
        asm volatile("s_waitcnt vmcnt(0)" ::: "memory");  // last tile: drain
      __builtin_amdgcn_sched_barrier(0);
      __builtin_amdgcn_s_barrier();
      __builtin_amdgcn_sched_barrier(0);
    }
  }

#pragma unroll
  for (int m = 0; m < 8; ++m)
#pragma unroll
    for (int n = 0; n < 2; ++n) {
      int col = by * 128 + wc * 32 + n * 16 + l15;
      float bval = bias[col];
#pragma unroll
      for (int i = 0; i < 4; ++i) {
        int row = bx * 256 + wr * 128 + m * 16 + lg * 4 + i;
        float v = acc[m][n][i] + bval;
        if (OUT_F16)
          ((u16*)outp)[(size_t)row * Nout + col] = f2h(v);
        else
          ((float*)outp)[(size_t)row * Nout + col] = v;
      }
    }
}

// K fragment pre-pack: kf chunk g (16B) holds K[key = kh*32 + l31][d-slice (df*2+hi)*8]
// g = ((((bh*32 + t)*2 + kh)*4 + df)*64 + l)
__global__ __launch_bounds__(256) void kfrag_prep(const u16* __restrict__ qkv,
                                                  u16* __restrict__ kf) {
  int g = blockIdx.x * 256 + threadIdx.x;
  int l = g & 63;
  int df = (g >> 6) & 3;
  int kh = (g >> 8) & 1;
  int t = (g >> 9) & 31;
  int bh = g >> 14;
  int b = bh >> 4, h = bh & 15;
  const u16* src = qkv + (size_t)(b * N_ + t * 64 + kh * 32 + (l & 31)) * C3 +
                   C_ + h * D_ + (df * 2 + (l >> 5)) * 8;
  *(short8*)(kf + (size_t)g * 8) = *(const short8*)src;
}

// V fragment pre-pack (transpose + REGISTER-ORDER key permutation):
// vf chunk (vh,kc) elem jj holds V^T[d = vh*32 + l31][key = kc*16 + (jj&3) + 8*(jj>>2) + 4*hi]
// chunk = ((((bh*32 + t)*2 + vh)*4 + kc)*64 + l)   [vh*4+kc = combo]
__global__ __launch_bounds__(256) void vfrag_prep(const u16* __restrict__ qkv,
                                                  u16* __restrict__ vf) {
  __shared__ u16 tile[64][72];
  const int tid = threadIdx.x;
  const int bh = blockIdx.y, b = bh >> 4, h = bh & 15;
  const int t = blockIdx.x;
  const int r = tid >> 3, c8 = (tid & 7) * 8;
#pragma unroll
  for (int rr = 0; rr < 2; ++rr) {
    int row = rr * 32 + r;
    short8 v = *(const short8*)(qkv + (size_t)(b * N_ + t * 64 + row) * C3 +
                                2 * C_ + h * D_ + c8);
    *(short8*)&tile[row][c8] = v;
  }
  __syncthreads();
  const int l = tid & 63, wv = tid >> 6;
  const int l31 = l & 31, hi = l >> 5;
#pragma unroll
  for (int i = 0; i < 2; ++i) {
    int combo = wv * 2 + i;
    int vh = combo >> 2, kc = combo & 3;
    short8 o;
#pragma unroll
    for (int jj = 0; jj < 8; ++jj)
      o[jj] = (short)tile[kc * 16 + (jj & 3) + 8 * (jj >> 2) + 4 * hi][vh * 32 + l31];
    *(short8*)(vf + ((size_t)(bh * 32 + t) * 8 + combo) * 512 + l * 8) = o;
  }
}

// Flash attention (fp16, static-max softmax, NO LDS/barriers in the main loop).
// 64 q-rows per wave (two q-sets A/B share every K/V fragment read).
// KV-split across wave pairs; pair combine via LDS at the end (validated r14/15).
// Block = 256 threads covering 128 q; grid (16, 64) XCD-swizzled.
__global__ __launch_bounds__(256, 2) void attn_fused(const u16* __restrict__ qkv,
                                                     const u16* __restrict__ kf,
                                                     const u16* __restrict__ vf,
                                                     u16* __restrict__ att) {
  __shared__ float red[2][64][68];   // [qg][lane][64 acc + 2 lrow] (pair exchange)
  const int tid = threadIdx.x;
  const int w = tid >> 6, l = tid & 63;
  const int l31 = l & 31, hi = l >> 5;
  const int qg = w >> 1, kvh = w & 1;
  int bid = blockIdx.y * gridDim.x + blockIdx.x;
  int swz = (bid & 7) * 128 + (bid >> 3);      // 1024 blocks -> 128 per XCD
  const int qt = swz & 15, bh = swz >> 4;
  const int b = bh >> 4, h = bh & 15;
  const int qb = qt * 128 + qg * 64;           // wave covers q [qb, qb+64)

  const float sc2 = 0.125f * 1.4426950408889634f;  // scale * log2(e)
  half8 qfA[4], qfB[4];
  {
    const _Float16 sch = (_Float16)sc2;
    const u16* qrowA = qkv + (size_t)(b * N_ + qb + l31) * C3 + h * D_ + hi * 8;
    const u16* qrowB = qrowA + (size_t)32 * C3;
#pragma unroll
    for (int df = 0; df < 4; ++df) {
      half8 qa = __builtin_bit_cast(half8, *(const short8*)(qrowA + df * 16));
      half8 qc = __builtin_bit_cast(half8, *(const short8*)(qrowB + df * 16));
#pragma unroll
      for (int j = 0; j < 8; ++j) { qa[j] *= sch; qc[j] *= sch; }
      qfA[df] = qa;
      qfB[df] = qc;
    }
  }

  f32x16 aA0, aA1, aB0, aB1;  // O^T tiles per set (d 0..31 / 32..63), col q = l31
#pragma unroll
  for (int j = 0; j < 16; ++j) { aA0[j] = 0.f; aA1[j] = 0.f; aB0[j] = 0.f; aB1[j] = 0.f; }
  float lrowA = 0.f, lrowB = 0.f;

  const u16* kp = kf + (size_t)bh * 32 * 4096;
  const u16* vp = vf + (size_t)bh * 32 * 4096;
  const int loff = l * 8;

#define MKPF(SV, J0, OUT)                                                      \
  {                                                                            \
    u32x4 wq = {pk2h(SV[J0 + 0], SV[J0 + 1]), pk2h(SV[J0 + 2], SV[J0 + 3]),   \
                pk2h(SV[J0 + 4], SV[J0 + 5]), pk2h(SV[J0 + 6], SV[J0 + 7])};   \
    OUT = __builtin_bit_cast(half8, wq);                                       \
  }

  const int t0 = kvh * 16;
  const int trot = qg * 8;                     // phase-offset between qg pairs
  for (int i = 0; i < 16; ++i) {
    const int t = t0 + ((i + trot) & 15);
    const u16* kt = kp + t * 4096;
    const u16* vt = vp + t * 4096;

    // K fragments (shared by both q-sets)
    half8 kfr[2][4];
#pragma unroll
    for (int kh = 0; kh < 2; ++kh)
#pragma unroll
      for (int df = 0; df < 4; ++df)
        kfr[kh][df] = __builtin_bit_cast(half8,
            *(const short8*)(kt + ((kh * 4 + df) * 64) * 8 + loff));

    // ---- set A: S = K Q_A^T -> exp -> pack (sA dies before sB is born) ----
    f32x16 sA0, sA1;
#pragma unroll
    for (int j = 0; j < 16; ++j) { sA0[j] = 0.f; sA1[j] = 0.f; }
#pragma unroll
    for (int df = 0; df < 4; ++df) {
      sA0 = __builtin_amdgcn_mfma_f32_32x32x16_f16(kfr[0][df], qfA[df], sA0, 0, 0, 0);
      sA1 = __builtin_amdgcn_mfma_f32_32x32x16_f16(kfr[1][df], qfA[df], sA1, 0, 0, 0);
    }
    float suA[4] = {0.f, 0.f, 0.f, 0.f};
#pragma unroll
    for (int j = 0; j < 16; ++j) {
      sA0[j] = __builtin_amdgcn_exp2f(sA0[j]);
      suA[j & 3] += sA0[j];
    }
#pragma unroll
    for (int j = 0; j < 16; ++j) {
      sA1[j] = __builtin_amdgcn_exp2f(sA1[j]);
      suA[j & 3] += sA1[j];
    }
    lrowA += (suA[0] + suA[1]) + (suA[2] + suA[3]);
    half8 pfA0, pfA1, pfA2, pfA3;
    MKPF(sA0, 0, pfA0)
    MKPF(sA0, 8, pfA1)
    MKPF(sA1, 0, pfA2)
    MKPF(sA1, 8, pfA3)

    // ---- set B: S = K Q_B^T (kfr dies here) ----
    f32x16 sB0, sB1;
#pragma unroll
    for (int j = 0; j < 16; ++j) { sB0[j] = 0.f; sB1[j] = 0.f; }
#pragma unroll
    for (int df = 0; df < 4; ++df) {
      sB0 = __builtin_amdgcn_mfma_f32_32x32x16_f16(kfr[0][df], qfB[df], sB0, 0, 0, 0);
      sB1 = __builtin_amdgcn_mfma_f32_32x32x16_f16(kfr[1][df], qfB[df], sB1, 0, 0, 0);
    }

    // V fragments (shared by both q-sets; issued under set-B softmax)
    half8 vfr[2][4];
#pragma unroll
    for (int vh = 0; vh < 2; ++vh)
#pragma unroll
      for (int kc = 0; kc < 4; ++kc)
        vfr[vh][kc] = __builtin_bit_cast(half8,
            *(const short8*)(vt + ((vh * 4 + kc) * 64) * 8 + loff));

    float suB[4] = {0.f, 0.f, 0.f, 0.f};
#pragma unroll
    for (int j = 0; j < 16; ++j) {
      sB0[j] = __builtin_amdgcn_exp2f(sB0[j]);
      suB[j & 3] += sB0[j];
    }
#pragma unroll
    for (int j = 0; j < 16; ++j) {
      sB1[j] = __builtin_amdgcn_exp2f(sB1[j]);
      suB[j & 3] += sB1[j];
    }
    lrowB += (suB[0] + suB[1]) + (suB[2] + suB[3]);
    half8 pfB0, pfB1, pfB2, pfB3;
    MKPF(sB0, 0, pfB0)
    MKPF(sB0, 8, pfB1)
    MKPF(sB1, 0, pfB2)
    MKPF(sB1, 8, pfB3)

    // ---- PV for both sets (vfr shared) ----
    aA0 = __builtin_amdgcn_mfma_f32_32x32x16_f16(vfr[0][0], pfA0, aA0, 0, 0, 0);
    aA1 = __builtin_amdgcn_mfma_f32_32x32x16_f16(vfr[1][0], pfA0, aA1, 0, 0, 0);
    aB0 = __builtin_amdgcn_mfma_f32_32x32x16_f16(vfr[0][0], pfB0, aB0, 0, 0, 0);
    aB1 = __builtin_amdgcn_mfma_f32_32x32x16_f16(vfr[1][0], pfB0, aB1, 0, 0, 0);
    aA0 = __builtin_amdgcn_mfma_f32_32x32x16_f16(vfr[0][1], pfA1, aA0, 0, 0, 0);
    aA1 = __builtin_amdgcn_mfma_f32_32x32x16_f16(vfr[1][1], pfA1, aA1, 0, 0, 0);
    aB0 = __builtin_amdgcn_mfma_f32_32x32x16_f16(vfr[0][1], pfB1, aB0, 0, 0, 0);
    aB1 = __builtin_amdgcn_mfma_f32_32x32x16_f16(vfr[1][1], pfB1, aB1, 0, 0, 0);
    aA0 = __builtin_amdgcn_mfma_f32_32x32x16_f16(vfr[0][2], pfA2, aA0, 0, 0, 0);
    aA1 = __builtin_amdgcn_mfma_f32_32x32x16_f16(vfr[1][2], pfA2, aA1, 0, 0, 0);
    aB0 = __builtin_amdgcn_mfma_f32_32x32x16_f16(vfr[0][2], pfB2, aB0, 0, 0, 0);
    aB1 = __builtin_amdgcn_mfma_f32_32x32x16_f16(vfr[1][2], pfB2, aB1, 0, 0, 0);
    aA0 = __builtin_amdgcn_mfma_f32_32x32x16_f16(vfr[0][3], pfA3, aA0, 0, 0, 0);
    aA1 = __builtin_amdgcn_mfma_f32_32x32x16_f16(vfr[1][3], pfA3, aA1, 0, 0, 0);
    aB0 = __builtin_amdgcn_mfma_f32_32x32x16_f16(vfr[0][3], pfB3, aB0, 0, 0, 0);
    aB1 = __builtin_amdgcn_mfma_f32_32x32x16_f16(vfr[1][3], pfB3, aB1, 0, 0, 0);
  }
#undef MKPF

  // pair combine: kvh=1 waves deposit partials; kvh=0 waves add and store.
  if (kvh) {
    float* s = &red[qg][l][0];
#pragma unroll
    for (int j = 0; j < 16; ++j) {
      s[j] = aA0[j];
      s[16 + j] = aA1[j];
      s[32 + j] = aB0[j];
      s[48 + j] = aB1[j];
    }
    s[64] = lrowA;
    s[65] = lrowB;
  }
  __syncthreads();
  if (!kvh) {
    const float* s = &red[qg][l][0];
#pragma unroll
    for (int j = 0; j < 16; ++j) {
      aA0[j] += s[j];
      aA1[j] += s[16 + j];
      aB0[j] += s[32 + j];
      aB1[j] += s[48 + j];
    }
    lrowA += s[64];
    lrowB += s[65];

    lrowA += __shfl_xor(lrowA, 32);
    lrowB += __shfl_xor(lrowB, 32);
    float rinvA = 1.0f / lrowA;
    float rinvB = 1.0f / lrowB;
    u16* orowA = att + (size_t)(b * N_ + qb + l31) * C_ + h * D_;
    u16* orowB = orowA + (size_t)32 * C_;
#pragma unroll
    for (int dt = 0; dt < 2; ++dt) {
#pragma unroll
      for (int r2 = 0; r2 < 4; ++r2) {
        int d0 = dt * 32 + r2 * 8 + hi * 4;
        s16x4 hvA, hvB;
#pragma unroll
        for (int i = 0; i < 4; ++i) {
          float vA = (dt ? aA1[r2 * 4 + i] : aA0[r2 * 4 + i]) * rinvA;
          float vB = (dt ? aB1[r2 * 4 + i] : aB0[r2 * 4 + i]) * rinvB;
          hvA[i] = (short)f2h(vA);
          hvB[i] = (short)f2h(vB);
        }
        *(s16x4*)(orowA + d0) = hvA;
        *(s16x4*)(orowB + d0) = hvB;
      }
    }
  }
}

extern "C" void kernel_launch(void* const* d_in, const int* in_sizes, int n_in,
                              void* d_out, int out_size, void* d_ws, size_t ws_size,
                              hipStream_t stream) {
  const float* x = (const float*)d_in[0];
  const float* w_qkv = (const float*)d_in[1];
  const float* b_qkv = (const float*)d_in[2];
  const float* w_proj = (const float*)d_in[3];
  const float* b_proj = (const float*)d_in[4];

  char* ws = (char*)d_ws;
  u16* qkv  = (u16*)(ws + 0);            // 8192*3072*2 = 50331648
  u16* x16  = (u16*)(ws + 50331648);     // 16777216
  u16* wq16 = (u16*)(ws + 67108864);     //  6291456
  u16* wp16 = (u16*)(ws + 73400320);     //  2097152
  u16* kf   = (u16*)(ws + 75497472);     // 16777216  (K fragments)
  u16* vf   = (u16*)(ws + 92274688);     // 16777216  (V fragments)
  u16* att  = (u16*)(ws + 109051904);    // 16777216

  f32_to_f16<<<4096, 256, 0, stream>>>(x, x16, M_ * C_ / 8);
  f32_to_f16<<<1536, 256, 0, stream>>>(w_qkv, wq16, 3 * C_ * C_ / 8);
  f32_to_f16<<<512, 256, 0, stream>>>(w_proj, wp16, C_ * C_ / 8);

  gemm_bt<true><<<dim3(32, 24), 512, 0, stream>>>(x16, wq16, b_qkv, qkv, C3);

  kfrag_prep<<<4096, 256, 0, stream>>>(qkv, kf);
  vfrag_prep<<<dim3(32, 64), 256, 0, stream>>>(qkv, vf);

  attn_fused<<<dim3(16, 64), 256, 0, stream>>>(qkv, kf, vf, att);

  gemm_bt<false><<<dim3(32, 8), 512, 0, stream>>>(att, wp16, b_proj, d_out, C_);
}

// Round 17
// 207.265 us; speedup vs baseline: 1.1740x; 1.1740x over previous
//
#include <hip/hip_runtime.h>

typedef unsigned short u16;
typedef __attribute__((ext_vector_type(8))) short short8;    // 8 x 16-bit payload
typedef __attribute__((ext_vector_type(4))) short s16x4;
typedef __attribute__((ext_vector_type(8))) _Float16 half8;  // MFMA f16 A/B frag
typedef __attribute__((ext_vector_type(4))) float f32x4;
typedef __attribute__((ext_vector_type(16))) float f32x16;
typedef __attribute__((ext_vector_type(4))) unsigned int u32x4;

#define DEVI static __device__ __forceinline__

static constexpr int B_ = 4, N_ = 2048, C_ = 1024, H_ = 16, D_ = 64;
static constexpr int M_ = B_ * N_;   // 8192
static constexpr int C3 = 3072;      // qkv row stride (3C)

DEVI u16 f2h(float f) {
  _Float16 h = (_Float16)f;          // v_cvt_f16_f32, RTN
  return __builtin_bit_cast(u16, h);
}

DEVI unsigned pk2h(float lo, float hi) {  // pack 2 f32 -> 2 f16 (lo in [15:0])
  return __builtin_bit_cast(unsigned, __builtin_amdgcn_cvt_pkrtz(lo, hi));
}

DEVI void gload_lds16(const void* g, void* lds) {
  __builtin_amdgcn_global_load_lds(
      (const __attribute__((address_space(1))) unsigned int*)g,
      (__attribute__((address_space(3))) unsigned int*)lds, 16, 0, 0);
}

// f32 -> f16 cast, 8 elems/thread
__global__ __launch_bounds__(256) void f32_to_f16(const float* __restrict__ src,
                                                  u16* __restrict__ dst, int n8) {
  int idx = blockIdx.x * 256 + threadIdx.x;
  if (idx >= n8) return;
  const float* s = src + (size_t)idx * 8;
  f32x4 f0 = *(const f32x4*)s;
  f32x4 f1 = *(const f32x4*)(s + 4);
  short8 o;
#pragma unroll
  for (int j = 0; j < 8; ++j) o[j] = (short)f2h(j < 4 ? f0[j] : f1[j - 4]);
  *(short8*)(dst + (size_t)idx * 8) = o;
}

// C[M][Nout] = A[M][1024] * B[Nout][1024]^T + bias.  128x128 tile, BK=32, 4 waves.
// Round 17: validated round-5 structure + LDS chunk swizzle col^=(row>>1)&3.
// A wave's b128 fragment read (16 consecutive rows at one 16B chunk) previously
// hit only 2 of 8 16B-slots per 128B stripe (4x over b128's 8-cycle minimum,
// 1.9e7 SQ_LDS_BANK_CONFLICT). Swizzle spreads 8 consecutive rows over all 8
// slots -> conflict-free. Applied per rule 21: linear LDS dest (global_load_lds
// requirement) + inverse-permuted GLOBAL source chunk + swizzled read chunk;
// both are per-thread constants (zero loop cost).
template <bool OUT_F16>
__global__ __launch_bounds__(256) void gemm_bt(const u16* __restrict__ A,
                                               const u16* __restrict__ Bm,
                                               const float* __restrict__ bias,
                                               void* __restrict__ outp, int Nout) {
  __shared__ u16 As[128 * 32];
  __shared__ u16 Bs[128 * 32];
  const int tid = threadIdx.x;
  const int w = tid >> 6, l = tid & 63;
  const int wr = w >> 1, wc = w & 1;
  const int l15 = l & 15, lg = l >> 4;
  const int nx = gridDim.x;
  int bid = blockIdx.y * nx + blockIdx.x;
  int cpx = (nx * gridDim.y) >> 3;
  int swz = (bid & 7) * cpx + (bid >> 3);
  int bx = swz % nx, by = swz / nx;
  const u16* Ab = A + (size_t)(bx * 128) * C_;
  const u16* Bb = Bm + (size_t)(by * 128) * C_;
  const int arow = tid >> 2;
  // staging chunk: LDS chunk (row=arow, col=tid&3) holds global col (tid&3)^((arow>>1)&3)
  const int ac8 = (((tid & 3) ^ ((tid >> 3) & 3)) * 8);
  // fragment read chunk: global col lg lives at LDS col lg^((row>>1)&3) = lg^((l15>>1)&3)
  const int lgs = lg ^ ((l15 >> 1) & 3);
  f32x4 acc[4][4];
#pragma unroll
  for (int m = 0; m < 4; ++m)
#pragma unroll
    for (int n = 0; n < 4; ++n) acc[m][n] = (f32x4){0.f, 0.f, 0.f, 0.f};

  for (int kt = 0; kt < C_; kt += 32) {
    __syncthreads();
#pragma unroll
    for (int i = 0; i < 2; ++i) {
      gload_lds16(Ab + (size_t)(i * 64 + arow) * C_ + kt + ac8,
                  (char*)As + (i * 64 + w * 16) * 64);
      gload_lds16(Bb + (size_t)(i * 64 + arow) * C_ + kt + ac8,
                  (char*)Bs + (i * 64 + w * 16) * 64);
    }
    __syncthreads();
    half8 af[4], bf[4];
#pragma unroll
    for (int m = 0; m < 4; ++m)
      af[m] = __builtin_bit_cast(half8, *(const short8*)((const char*)As +
                  (wr * 64 + m * 16 + l15) * 64 + lgs * 16));
#pragma unroll
    for (int n = 0; n < 4; ++n)
      bf[n] = __builtin_bit_cast(half8, *(const short8*)((const char*)Bs +
                  (wc * 64 + n * 16 + l15) * 64 + lgs * 16));
#pragma unroll
    for (int m = 0; m < 4; ++m)
#pragma unroll
      for (int n = 0; n < 4; ++n)
        acc[m][n] = __builtin_amdgcn_mfma_f32_16x16x32_f16(af[m], bf[n], acc[m][n], 0, 0, 0);
  }
#pragma unroll
  for (int m = 0; m < 4; ++m)
#pragma unroll
    for (int n = 0; n < 4; ++n) {
      int col = by * 128 + wc * 64 + n * 16 + l15;
      float bval = bias[col];
#pragma unroll
      for (int i = 0; i < 4; ++i) {
        int row = bx * 128 + wr * 64 + m * 16 + lg * 4 + i;
        float v = acc[m][n][i] + bval;
        if (OUT_F16)
          ((u16*)outp)[(size_t)row * Nout + col] = f2h(v);
        else
          ((float*)outp)[(size_t)row * Nout + col] = v;
      }
    }
}

// K fragment pre-pack: kf chunk g (16B) holds K[key = kh*32 + l31][d-slice (df*2+hi)*8]
// g = ((((bh*32 + t)*2 + kh)*4 + df)*64 + l)
__global__ __launch_bounds__(256) void kfrag_prep(const u16* __restrict__ qkv,
                                                  u16* __restrict__ kf) {
  int g = blockIdx.x * 256 + threadIdx.x;
  int l = g & 63;
  int df = (g >> 6) & 3;
  int kh = (g >> 8) & 1;
  int t = (g >> 9) & 31;
  int bh = g >> 14;
  int b = bh >> 4, h = bh & 15;
  const u16* src = qkv + (size_t)(b * N_ + t * 64 + kh * 32 + (l & 31)) * C3 +
                   C_ + h * D_ + (df * 2 + (l >> 5)) * 8;
  *(short8*)(kf + (size_t)g * 8) = *(const short8*)src;
}

// V fragment pre-pack (transpose + REGISTER-ORDER key permutation):
// vf chunk (vh,kc) elem jj holds V^T[d = vh*32 + l31][key = kc*16 + (jj&3) + 8*(jj>>2) + 4*hi]
// chunk = ((((bh*32 + t)*2 + vh)*4 + kc)*64 + l)   [vh*4+kc = combo]
__global__ __launch_bounds__(256) void vfrag_prep(const u16* __restrict__ qkv,
                                                  u16* __restrict__ vf) {
  __shared__ u16 tile[64][72];
  const int tid = threadIdx.x;
  const int bh = blockIdx.y, b = bh >> 4, h = bh & 15;
  const int t = blockIdx.x;
  const int r = tid >> 3, c8 = (tid & 7) * 8;
#pragma unroll
  for (int rr = 0; rr < 2; ++rr) {
    int row = rr * 32 + r;
    short8 v = *(const short8*)(qkv + (size_t)(b * N_ + t * 64 + row) * C3 +
                                2 * C_ + h * D_ + c8);
    *(short8*)&tile[row][c8] = v;
  }
  __syncthreads();
  const int l = tid & 63, wv = tid >> 6;
  const int l31 = l & 31, hi = l >> 5;
#pragma unroll
  for (int i = 0; i < 2; ++i) {
    int combo = wv * 2 + i;
    int vh = combo >> 2, kc = combo & 3;
    short8 o;
#pragma unroll
    for (int jj = 0; jj < 8; ++jj)
      o[jj] = (short)tile[kc * 16 + (jj & 3) + 8 * (jj >> 2) + 4 * hi][vh * 32 + l31];
    *(short8*)(vf + ((size_t)(bh * 32 + t) * 8 + combo) * 512 + l * 8) = o;
  }
}

// Flash attention (fp16, static-max softmax, NO LDS/barriers in the main loop).
// 64 q-rows per wave (two q-sets A/B share every K/V fragment read).
// KV-split across wave pairs; pair combine via LDS at the end (validated r14/15).
// Block = 256 threads covering 128 q; grid (16, 64) XCD-swizzled.
__global__ __launch_bounds__(256, 2) void attn_fused(const u16* __restrict__ qkv,
                                                     const u16* __restrict__ kf,
                                                     const u16* __restrict__ vf,
                                                     u16* __restrict__ att) {
  __shared__ float red[2][64][68];   // [qg][lane][64 acc + 2 lrow] (pair exchange)
  const int tid = threadIdx.x;
  const int w = tid >> 6, l = tid & 63;
  const int l31 = l & 31, hi = l >> 5;
  const int qg = w >> 1, kvh = w & 1;
  int bid = blockIdx.y * gridDim.x + blockIdx.x;
  int swz = (bid & 7) * 128 + (bid >> 3);      // 1024 blocks -> 128 per XCD
  const int qt = swz & 15, bh = swz >> 4;
  const int b = bh >> 4, h = bh & 15;
  const int qb = qt * 128 + qg * 64;           // wave covers q [qb, qb+64)

  const float sc2 = 0.125f * 1.4426950408889634f;  // scale * log2(e)
  half8 qfA[4], qfB[4];
  {
    const _Float16 sch = (_Float16)sc2;
    const u16* qrowA = qkv + (size_t)(b * N_ + qb + l31) * C3 + h * D_ + hi * 8;
    const u16* qrowB = qrowA + (size_t)32 * C3;
#pragma unroll
    for (int df = 0; df < 4; ++df) {
      half8 qa = __builtin_bit_cast(half8, *(const short8*)(qrowA + df * 16));
      half8 qc = __builtin_bit_cast(half8, *(const short8*)(qrowB + df * 16));
#pragma unroll
      for (int j = 0; j < 8; ++j) { qa[j] *= sch; qc[j] *= sch; }
      qfA[df] = qa;
      qfB[df] = qc;
    }
  }

  f32x16 aA0, aA1, aB0, aB1;  // O^T tiles per set (d 0..31 / 32..63), col q = l31
#pragma unroll
  for (int j = 0; j < 16; ++j) { aA0[j] = 0.f; aA1[j] = 0.f; aB0[j] = 0.f; aB1[j] = 0.f; }
  float lrowA = 0.f, lrowB = 0.f;

  const u16* kp = kf + (size_t)bh * 32 * 4096;
  const u16* vp = vf + (size_t)bh * 32 * 4096;
  const int loff = l * 8;

#define MKPF(SV, J0, OUT)                                                      \
  {                                                                            \
    u32x4 wq = {pk2h(SV[J0 + 0], SV[J0 + 1]), pk2h(SV[J0 + 2], SV[J0 + 3]),   \
                pk2h(SV[J0 + 4], SV[J0 + 5]), pk2h(SV[J0 + 6], SV[J0 + 7])};   \
    OUT = __builtin_bit_cast(half8, wq);                                       \
  }

  const int t0 = kvh * 16;
  const int trot = qg * 8;                     // phase-offset between qg pairs
  for (int i = 0; i < 16; ++i) {
    const int t = t0 + ((i + trot) & 15);
    const u16* kt = kp + t * 4096;
    const u16* vt = vp + t * 4096;

    // K fragments (shared by both q-sets)
    half8 kfr[2][4];
#pragma unroll
    for (int kh = 0; kh < 2; ++kh)
#pragma unroll
      for (int df = 0; df < 4; ++df)
        kfr[kh][df] = __builtin_bit_cast(half8,
            *(const short8*)(kt + ((kh * 4 + df) * 64) * 8 + loff));

    // ---- set A: S = K Q_A^T -> exp -> pack (sA dies before sB is born) ----
    f32x16 sA0, sA1;
#pragma unroll
    for (int j = 0; j < 16; ++j) { sA0[j] = 0.f; sA1[j] = 0.f; }
#pragma unroll
    for (int df = 0; df < 4; ++df) {
      sA0 = __builtin_amdgcn_mfma_f32_32x32x16_f16(kfr[0][df], qfA[df], sA0, 0, 0, 0);
      sA1 = __builtin_amdgcn_mfma_f32_32x32x16_f16(kfr[1][df], qfA[df], sA1, 0, 0, 0);
    }
    float suA[4] = {0.f, 0.f, 0.f, 0.f};
#pragma unroll
    for (int j = 0; j < 16; ++j) {
      sA0[j] = __builtin_amdgcn_exp2f(sA0[j]);
      suA[j & 3] += sA0[j];
    }
#pragma unroll
    for (int j = 0; j < 16; ++j) {
      sA1[j] = __builtin_amdgcn_exp2f(sA1[j]);
      suA[j & 3] += sA1[j];
    }
    lrowA += (suA[0] + suA[1]) + (suA[2] + suA[3]);
    half8 pfA0, pfA1, pfA2, pfA3;
    MKPF(sA0, 0, pfA0)
    MKPF(sA0, 8, pfA1)
    MKPF(sA1, 0, pfA2)
    MKPF(sA1, 8, pfA3)

    // ---- set B: S = K Q_B^T (kfr dies here) ----
    f32x16 sB0, sB1;
#pragma unroll
    for (int j = 0; j < 16; ++j) { sB0[j] = 0.f; sB1[j] = 0.f; }
#pragma unroll
    for (int df = 0; df < 4; ++df) {
      sB0 = __builtin_amdgcn_mfma_f32_32x32x16_f16(kfr[0][df], qfB[df], sB0, 0, 0, 0);
      sB1 = __builtin_amdgcn_mfma_f32_32x32x16_f16(kfr[1][df], qfB[df], sB1, 0, 0, 0);
    }

    // V fragments (shared by both q-sets; issued under set-B softmax)
    half8 vfr[2][4];
#pragma unroll
    for (int vh = 0; vh < 2; ++vh)
#pragma unroll
      for (int kc = 0; kc < 4; ++kc)
        vfr[vh][kc] = __builtin_bit_cast(half8,
            *(const short8*)(vt + ((vh * 4 + kc) * 64) * 8 + loff));

    float suB[4] = {0.f, 0.f, 0.f, 0.f};
#pragma unroll
    for (int j = 0; j < 16; ++j) {
      sB0[j] = __builtin_amdgcn_exp2f(sB0[j]);
      suB[j & 3] += sB0[j];
    }
#pragma unroll
    for (int j = 0; j < 16; ++j) {
      sB1[j] = __builtin_amdgcn_exp2f(sB1[j]);
      suB[j & 3] += sB1[j];
    }
    lrowB += (suB[0] + suB[1]) + (suB[2] + suB[3]);
    half8 pfB0, pfB1, pfB2, pfB3;
    MKPF(sB0, 0, pfB0)
    MKPF(sB0, 8, pfB1)
    MKPF(sB1, 0, pfB2)
    MKPF(sB1, 8, pfB3)

    // ---- PV for both sets (vfr shared) ----
    aA0 = __builtin_amdgcn_mfma_f32_32x32x16_f16(vfr[0][0], pfA0, aA0, 0, 0, 0);
    aA1 = __builtin_amdgcn_mfma_f32_32x32x16_f16(vfr[1][0], pfA0, aA1, 0, 0, 0);
    aB0 = __builtin_amdgcn_mfma_f32_32x32x16_f16(vfr[0][0], pfB0, aB0, 0, 0, 0);
    aB1 = __builtin_amdgcn_mfma_f32_32x32x16_f16(vfr[1][0], pfB0, aB1, 0, 0, 0);
    aA0 = __builtin_amdgcn_mfma_f32_32x32x16_f16(vfr[0][1], pfA1, aA0, 0, 0, 0);
    aA1 = __builtin_amdgcn_mfma_f32_32x32x16_f16(vfr[1][1], pfA1, aA1, 0, 0, 0);
    aB0 = __builtin_amdgcn_mfma_f32_32x32x16_f16(vfr[0][1], pfB1, aB0, 0, 0, 0);
    aB1 = __builtin_amdgcn_mfma_f32_32x32x16_f16(vfr[1][1], pfB1, aB1, 0, 0, 0);
    aA0 = __builtin_amdgcn_mfma_f32_32x32x16_f16(vfr[0][2], pfA2, aA0, 0, 0, 0);
    aA1 = __builtin_amdgcn_mfma_f32_32x32x16_f16(vfr[1][2], pfA2, aA1, 0, 0, 0);
    aB0 = __builtin_amdgcn_mfma_f32_32x32x16_f16(vfr[0][2], pfB2, aB0, 0, 0, 0);
    aB1 = __builtin_amdgcn_mfma_f32_32x32x16_f16(vfr[1][2], pfB2, aB1, 0, 0, 0);
    aA0 = __builtin_amdgcn_mfma_f32_32x32x16_f16(vfr[0][3], pfA3, aA0, 0, 0, 0);
    aA1 = __builtin_amdgcn_mfma_f32_32x32x16_f16(vfr[1][3], pfA3, aA1, 0, 0, 0);
    aB0 = __builtin_amdgcn_mfma_f32_32x32x16_f16(vfr[0][3], pfB3, aB0, 0, 0, 0);
    aB1 = __builtin_amdgcn_mfma_f32_32x32x16_f16(vfr[1][3], pfB3, aB1, 0, 0, 0);
  }
#undef MKPF

  // pair combine: kvh=1 waves deposit partials; kvh=0 waves add and store.
  if (kvh) {
    float* s = &red[qg][l][0];
#pragma unroll
    for (int j = 0; j < 16; ++j) {
      s[j] = aA0[j];
      s[16 + j] = aA1[j];
      s[32 + j] = aB0[j];
      s[48 + j] = aB1[j];
    }
    s[64] = lrowA;
    s[65] = lrowB;
  }
  __syncthreads();
  if (!kvh) {
    const float* s = &red[qg][l][0];
#pragma unroll
    for (int j = 0; j < 16; ++j) {
      aA0[j] += s[j];
      aA1[j] += s[16 + j];
      aB0[j] += s[32 + j];
      aB1[j] += s[48 + j];
    }
    lrowA += s[64];
    lrowB += s[65];

    lrowA += __shfl_xor(lrowA, 32);
    lrowB += __shfl_xor(lrowB, 32);
    float rinvA = 1.0f / lrowA;
    float rinvB = 1.0f / lrowB;
    u16* orowA = att + (size_t)(b * N_ + qb + l31) * C_ + h * D_;
    u16* orowB = orowA + (size_t)32 * C_;
#pragma unroll
    for (int dt = 0; dt < 2; ++dt) {
#pragma unroll
      for (int r2 = 0; r2 < 4; ++r2) {
        int d0 = dt * 32 + r2 * 8 + hi * 4;
        s16x4 hvA, hvB;
#pragma unroll
        for (int i = 0; i < 4; ++i) {
          float vA = (dt ? aA1[r2 * 4 + i] : aA0[r2 * 4 + i]) * rinvA;
          float vB = (dt ? aB1[r2 * 4 + i] : aB0[r2 * 4 + i]) * rinvB;
          hvA[i] = (short)f2h(vA);
          hvB[i] = (short)f2h(vB);
        }
        *(s16x4*)(orowA + d0) = hvA;
        *(s16x4*)(orowB + d0) = hvB;
      }
    }
  }
}

extern "C" void kernel_launch(void* const* d_in, const int* in_sizes, int n_in,
                              void* d_out, int out_size, void* d_ws, size_t ws_size,
                              hipStream_t stream) {
  const float* x = (const float*)d_in[0];
  const float* w_qkv = (const float*)d_in[1];
  const float* b_qkv = (const float*)d_in[2];
  const float* w_proj = (const float*)d_in[3];
  const float* b_proj = (const float*)d_in[4];

  char* ws = (char*)d_ws;
  u16* qkv  = (u16*)(ws + 0);            // 8192*3072*2 = 50331648
  u16* x16  = (u16*)(ws + 50331648);     // 16777216
  u16* wq16 = (u16*)(ws + 67108864);     //  6291456
  u16* wp16 = (u16*)(ws + 73400320);     //  2097152
  u16* kf   = (u16*)(ws + 75497472);     // 16777216  (K fragments)
  u16* vf   = (u16*)(ws + 92274688);     // 16777216  (V fragments)
  u16* att  = (u16*)(ws + 109051904);    // 16777216

  f32_to_f16<<<4096, 256, 0, stream>>>(x, x16, M_ * C_ / 8);
  f32_to_f16<<<1536, 256, 0, stream>>>(w_qkv, wq16, 3 * C_ * C_ / 8);
  f32_to_f16<<<512, 256, 0, stream>>>(w_proj, wp16, C_ * C_ / 8);

  gemm_bt<true><<<dim3(64, 24), 256, 0, stream>>>(x16, wq16, b_qkv, qkv, C3);

  kfrag_prep<<<4096, 256, 0, stream>>>(qkv, kf);
  vfrag_prep<<<dim3(32, 64), 256, 0, stream>>>(qkv, vf);

  attn_fused<<<dim3(16, 64), 256, 0, stream>>>(qkv, kf, vf, att);

  gemm_bt<false><<<dim3(64, 8), 256, 0, stream>>>(att, wp16, b_proj, d_out, C_);
}

// Round 18
// 201.388 us; speedup vs baseline: 1.2082x; 1.0292x over previous
//
#include <hip/hip_runtime.h>

typedef unsigned short u16;
typedef __attribute__((ext_vector_type(8))) short short8;    // 8 x 16-bit payload
typedef __attribute__((ext_vector_type(4))) short s16x4;
typedef __attribute__((ext_vector_type(8))) _Float16 half8;  // MFMA f16 A/B frag
typedef __attribute__((ext_vector_type(4))) float f32x4;
typedef __attribute__((ext_vector_type(16))) float f32x16;
typedef __attribute__((ext_vector_type(4))) unsigned int u32x4;

#define DEVI static __device__ __forceinline__

static constexpr int B_ = 4, N_ = 2048, C_ = 1024, H_ = 16, D_ = 64;
static constexpr int M_ = B_ * N_;   // 8192
static constexpr int C3 = 3072;      // qkv row stride (3C)

DEVI u16 f2h(float f) {
  _Float16 h = (_Float16)f;          // v_cvt_f16_f32, RTN
  return __builtin_bit_cast(u16, h);
}

DEVI unsigned pk2h(float lo, float hi) {  // pack 2 f32 -> 2 f16 (lo in [15:0])
  return __builtin_bit_cast(unsigned, __builtin_amdgcn_cvt_pkrtz(lo, hi));
}

DEVI void gload_lds16(const void* g, void* lds) {
  __builtin_amdgcn_global_load_lds(
      (const __attribute__((address_space(1))) unsigned int*)g,
      (__attribute__((address_space(3))) unsigned int*)lds, 16, 0, 0);
}

// All three f32->f16 casts in one launch (x 1048576, w_qkv 393216, w_proj 131072
// 8-elem chunks; total 1572864 = 6144*256 exactly).
__global__ __launch_bounds__(256) void f32_to_f16_all(const float* __restrict__ x,
                                                      const float* __restrict__ wq,
                                                      const float* __restrict__ wp,
                                                      u16* __restrict__ x16,
                                                      u16* __restrict__ wq16,
                                                      u16* __restrict__ wp16) {
  int idx = blockIdx.x * 256 + threadIdx.x;
  const float* s;
  u16* d;
  int base;
  if (idx < 1048576) {
    s = x; d = x16; base = idx;
  } else if (idx < 1048576 + 393216) {
    s = wq; d = wq16; base = idx - 1048576;
  } else {
    s = wp; d = wp16; base = idx - 1441792;
  }
  const float* sp = s + (size_t)base * 8;
  f32x4 f0 = *(const f32x4*)sp;
  f32x4 f1 = *(const f32x4*)(sp + 4);
  short8 o;
#pragma unroll
  for (int j = 0; j < 8; ++j) o[j] = (short)f2h(j < 4 ? f0[j] : f1[j - 4]);
  *(short8*)(d + (size_t)base * 8) = o;
}

// C[M][Nout] = A[M][1024] * B[Nout][1024]^T + bias.  128x128 tile, 4 waves.
// Round 18: BK=64 (barrier amortization — 32 MFMA per barrier-pair instead of
// 16; the 2-phase critical path is stage+vmcnt+barrier per m233, so halving
// barrier events per MFMA is the lever; T2-style swizzle alone was null, as
// the regime gate predicts). 128B LDS rows need chunk^=(row&7) swizzle
// (row stride = 0 mod 32 banks): applied per rule 21 with linear LDS dest +
// inverse-permuted GLOBAL source chunk + swizzled read chunk (both per-thread
// constants). Bank balance verified: 8 lanes per 16B-slot-column = b128 minimum.
template <bool OUT_F16>
__global__ __launch_bounds__(256) void gemm_bt(const u16* __restrict__ A,
                                               const u16* __restrict__ Bm,
                                               const float* __restrict__ bias,
                                               void* __restrict__ outp, int Nout) {
  __shared__ u16 As[128 * 64];
  __shared__ u16 Bs[128 * 64];
  const int tid = threadIdx.x;
  const int w = tid >> 6, l = tid & 63;
  const int wr = w >> 1, wc = w & 1;
  const int l15 = l & 15, lg = l >> 4;
  const int e7 = l15 & 7;
  const int nx = gridDim.x;
  int bid = blockIdx.y * nx + blockIdx.x;
  int cpx = (nx * gridDim.y) >> 3;
  int swz = (bid & 7) * cpx + (bid >> 3);
  int bx = swz % nx, by = swz / nx;
  const u16* Ab = A + (size_t)(bx * 128) * C_;
  const u16* Bb = Bm + (size_t)(by * 128) * C_;
  // staging: chunk c = i*256+tid -> LDS row c>>3 = i*32+(tid>>3), chunk col tid&7;
  // that slot must hold global chunk (tid&7)^(row&7) = (tid&7)^((tid>>3)&7).
  const int srow = tid >> 3;
  const int sgc8 = (((tid & 7) ^ ((tid >> 3) & 7)) * 8);   // source u16 offset
  // fragment read: global chunk kk*4+lg lives at LDS chunk (kk*4+lg)^(l15&7)
  const int fc0 = (lg ^ e7) << 4;        // kk=0 byte offset
  const int fc1 = ((4 + lg) ^ e7) << 4;  // kk=1 byte offset
  f32x4 acc[4][4];
#pragma unroll
  for (int m = 0; m < 4; ++m)
#pragma unroll
    for (int n = 0; n < 4; ++n) acc[m][n] = (f32x4){0.f, 0.f, 0.f, 0.f};

  for (int kt = 0; kt < C_; kt += 64) {
    __syncthreads();
#pragma unroll
    for (int i = 0; i < 4; ++i) {
      int r = i * 32 + srow;
      gload_lds16(Ab + (size_t)r * C_ + kt + sgc8, (char*)As + i * 4096 + w * 1024);
      gload_lds16(Bb + (size_t)r * C_ + kt + sgc8, (char*)Bs + i * 4096 + w * 1024);
    }
    __syncthreads();
#pragma unroll
    for (int kk = 0; kk < 2; ++kk) {
      const int fco = kk ? fc1 : fc0;
      half8 af[4], bf[4];
#pragma unroll
      for (int m = 0; m < 4; ++m)
        af[m] = __builtin_bit_cast(half8, *(const short8*)((const char*)As +
                    (wr * 64 + m * 16 + l15) * 128 + fco));
#pragma unroll
      for (int n = 0; n < 4; ++n)
        bf[n] = __builtin_bit_cast(half8, *(const short8*)((const char*)Bs +
                    (wc * 64 + n * 16 + l15) * 128 + fco));
#pragma unroll
      for (int m = 0; m < 4; ++m)
#pragma unroll
        for (int n = 0; n < 4; ++n)
          acc[m][n] = __builtin_amdgcn_mfma_f32_16x16x32_f16(af[m], bf[n], acc[m][n], 0, 0, 0);
    }
  }
#pragma unroll
  for (int m = 0; m < 4; ++m)
#pragma unroll
    for (int n = 0; n < 4; ++n) {
      int col = by * 128 + wc * 64 + n * 16 + l15;
      float bval = bias[col];
#pragma unroll
      for (int i = 0; i < 4; ++i) {
        int row = bx * 128 + wr * 64 + m * 16 + lg * 4 + i;
        float v = acc[m][n][i] + bval;
        if (OUT_F16)
          ((u16*)outp)[(size_t)row * Nout + col] = f2h(v);
        else
          ((float*)outp)[(size_t)row * Nout + col] = v;
      }
    }
}

// Merged K/V fragment pre-pack: blocks [0,4096) do kfrag, [4096,6144) do vfrag.
// kfrag: kf chunk g (16B) holds K[key = kh*32 + l31][d-slice (df*2+hi)*8],
//        g = ((((bh*32 + t)*2 + kh)*4 + df)*64 + l).
// vfrag: vf chunk (vh,kc) elem jj holds
//        V^T[d = vh*32 + l31][key = kc*16 + (jj&3) + 8*(jj>>2) + 4*hi]
//        (register-order key permutation matching the MFMA C-layout).
__global__ __launch_bounds__(256) void kv_prep(const u16* __restrict__ qkv,
                                               u16* __restrict__ kf,
                                               u16* __restrict__ vf) {
  __shared__ u16 tile[64][72];
  const int bxk = blockIdx.x;
  if (bxk < 4096) {
    int g = bxk * 256 + threadIdx.x;
    int l = g & 63;
    int df = (g >> 6) & 3;
    int kh = (g >> 8) & 1;
    int t = (g >> 9) & 31;
    int bh = g >> 14;
    int b = bh >> 4, h = bh & 15;
    const u16* src = qkv + (size_t)(b * N_ + t * 64 + kh * 32 + (l & 31)) * C3 +
                     C_ + h * D_ + (df * 2 + (l >> 5)) * 8;
    *(short8*)(kf + (size_t)g * 8) = *(const short8*)src;
    return;
  }
  const int idx2 = bxk - 4096;
  const int t = idx2 & 31, bh = idx2 >> 5;
  const int b = bh >> 4, h = bh & 15;
  const int tid = threadIdx.x;
  const int r = tid >> 3, c8 = (tid & 7) * 8;
#pragma unroll
  for (int rr = 0; rr < 2; ++rr) {
    int row = rr * 32 + r;
    short8 v = *(const short8*)(qkv + (size_t)(b * N_ + t * 64 + row) * C3 +
                                2 * C_ + h * D_ + c8);
    *(short8*)&tile[row][c8] = v;
  }
  __syncthreads();
  const int l = tid & 63, wv = tid >> 6;
  const int l31 = l & 31, hi = l >> 5;
#pragma unroll
  for (int i = 0; i < 2; ++i) {
    int combo = wv * 2 + i;
    int vh = combo >> 2, kc = combo & 3;
    short8 o;
#pragma unroll
    for (int jj = 0; jj < 8; ++jj)
      o[jj] = (short)tile[kc * 16 + (jj & 3) + 8 * (jj >> 2) + 4 * hi][vh * 32 + l31];
    *(short8*)(vf + ((size_t)(bh * 32 + t) * 8 + combo) * 512 + l * 8) = o;
  }
}

// Flash attention (fp16, static-max softmax, NO LDS/barriers in the main loop).
// 64 q-rows per wave (two q-sets A/B share every K/V fragment read).
// KV-split across wave pairs; pair combine via LDS at the end (validated r14-17).
// Block = 256 threads covering 128 q; grid (16, 64) XCD-swizzled.
__global__ __launch_bounds__(256, 2) void attn_fused(const u16* __restrict__ qkv,
                                                     const u16* __restrict__ kf,
                                                     const u16* __restrict__ vf,
                                                     u16* __restrict__ att) {
  __shared__ float red[2][64][68];   // [qg][lane][64 acc + 2 lrow] (pair exchange)
  const int tid = threadIdx.x;
  const int w = tid >> 6, l = tid & 63;
  const int l31 = l & 31, hi = l >> 5;
  const int qg = w >> 1, kvh = w & 1;
  int bid = blockIdx.y * gridDim.x + blockIdx.x;
  int swz = (bid & 7) * 128 + (bid >> 3);      // 1024 blocks -> 128 per XCD
  const int qt = swz & 15, bh = swz >> 4;
  const int b = bh >> 4, h = bh & 15;
  const int qb = qt * 128 + qg * 64;           // wave covers q [qb, qb+64)

  const float sc2 = 0.125f * 1.4426950408889634f;  // scale * log2(e)
  half8 qfA[4], qfB[4];
  {
    const _Float16 sch = (_Float16)sc2;
    const u16* qrowA = qkv + (size_t)(b * N_ + qb + l31) * C3 + h * D_ + hi * 8;
    const u16* qrowB = qrowA + (size_t)32 * C3;
#pragma unroll
    for (int df = 0; df < 4; ++df) {
      half8 qa = __builtin_bit_cast(half8, *(const short8*)(qrowA + df * 16));
      half8 qc = __builtin_bit_cast(half8, *(const short8*)(qrowB + df * 16));
#pragma unroll
      for (int j = 0; j < 8; ++j) { qa[j] *= sch; qc[j] *= sch; }
      qfA[df] = qa;
      qfB[df] = qc;
    }
  }

  f32x16 aA0, aA1, aB0, aB1;  // O^T tiles per set (d 0..31 / 32..63), col q = l31
#pragma unroll
  for (int j = 0; j < 16; ++j) { aA0[j] = 0.f; aA1[j] = 0.f; aB0[j] = 0.f; aB1[j] = 0.f; }
  float lrowA = 0.f, lrowB = 0.f;

  const u16* kp = kf + (size_t)bh * 32 * 4096;
  const u16* vp = vf + (size_t)bh * 32 * 4096;
  const int loff = l * 8;

#define MKPF(SV, J0, OUT)                                                      \
  {                                                                            \
    u32x4 wq = {pk2h(SV[J0 + 0], SV[J0 + 1]), pk2h(SV[J0 + 2], SV[J0 + 3]),   \
                pk2h(SV[J0 + 4], SV[J0 + 5]), pk2h(SV[J0 + 6], SV[J0 + 7])};   \
    OUT = __builtin_bit_cast(half8, wq);                                       \
  }

  const int t0 = kvh * 16;
  const int trot = qg * 8;                     // phase-offset between qg pairs
  for (int i = 0; i < 16; ++i) {
    const int t = t0 + ((i + trot) & 15);
    const u16* kt = kp + t * 4096;
    const u16* vt = vp + t * 4096;

    // K fragments (shared by both q-sets)
    half8 kfr[2][4];
#pragma unroll
    for (int kh = 0; kh < 2; ++kh)
#pragma unroll
      for (int df = 0; df < 4; ++df)
        kfr[kh][df] = __builtin_bit_cast(half8,
            *(const short8*)(kt + ((kh * 4 + df) * 64) * 8 + loff));

    // ---- set A: S = K Q_A^T -> exp -> pack (sA dies before sB is born) ----
    f32x16 sA0, sA1;
#pragma unroll
    for (int j = 0; j < 16; ++j) { sA0[j] = 0.f; sA1[j] = 0.f; }
#pragma unroll
    for (int df = 0; df < 4; ++df) {
      sA0 = __builtin_amdgcn_mfma_f32_32x32x16_f16(kfr[0][df], qfA[df], sA0, 0, 0, 0);
      sA1 = __builtin_amdgcn_mfma_f32_32x32x16_f16(kfr[1][df], qfA[df], sA1, 0, 0, 0);
    }
    float suA[4] = {0.f, 0.f, 0.f, 0.f};
#pragma unroll
    for (int j = 0; j < 16; ++j) {
      sA0[j] = __builtin_amdgcn_exp2f(sA0[j]);
      suA[j & 3] += sA0[j];
    }
#pragma unroll
    for (int j = 0; j < 16; ++j) {
      sA1[j] = __builtin_amdgcn_exp2f(sA1[j]);
      suA[j & 3] += sA1[j];
    }
    lrowA += (suA[0] + suA[1]) + (suA[2] + suA[3]);
    half8 pfA0, pfA1, pfA2, pfA3;
    MKPF(sA0, 0, pfA0)
    MKPF(sA0, 8, pfA1)
    MKPF(sA1, 0, pfA2)
    MKPF(sA1, 8, pfA3)

    // ---- set B: S = K Q_B^T (kfr dies here) ----
    f32x16 sB0, sB1;
#pragma unroll
    for (int j = 0; j < 16; ++j) { sB0[j] = 0.f; sB1[j] = 0.f; }
#pragma unroll
    for (int df = 0; df < 4; ++df) {
      sB0 = __builtin_amdgcn_mfma_f32_32x32x16_f16(kfr[0][df], qfB[df], sB0, 0, 0, 0);
      sB1 = __builtin_amdgcn_mfma_f32_32x32x16_f16(kfr[1][df], qfB[df], sB1, 0, 0, 0);
    }

    // V fragments (shared by both q-sets; issued under set-B softmax)
    half8 vfr[2][4];
#pragma unroll
    for (int vh = 0; vh < 2; ++vh)
#pragma unroll
      for (int kc = 0; kc < 4; ++kc)
        vfr[vh][kc] = __builtin_bit_cast(half8,
            *(const short8*)(vt + ((vh * 4 + kc) * 64) * 8 + loff));

    float suB[4] = {0.f, 0.f, 0.f, 0.f};
#pragma unroll
    for (int j = 0; j < 16; ++j) {
      sB0[j] = __builtin_amdgcn_exp2f(sB0[j]);
      suB[j & 3] += sB0[j];
    }
#pragma unroll
    for (int j = 0; j < 16; ++j) {
      sB1[j] = __builtin_amdgcn_exp2f(sB1[j]);
      suB[j & 3] += sB1[j];
    }
    lrowB += (suB[0] + suB[1]) + (suB[2] + suB[3]);
    half8 pfB0, pfB1, pfB2, pfB3;
    MKPF(sB0, 0, pfB0)
    MKPF(sB0, 8, pfB1)
    MKPF(sB1, 0, pfB2)
    MKPF(sB1, 8, pfB3)

    // ---- PV for both sets (vfr shared) ----
    aA0 = __builtin_amdgcn_mfma_f32_32x32x16_f16(vfr[0][0], pfA0, aA0, 0, 0, 0);
    aA1 = __builtin_amdgcn_mfma_f32_32x32x16_f16(vfr[1][0], pfA0, aA1, 0, 0, 0);
    aB0 = __builtin_amdgcn_mfma_f32_32x32x16_f16(vfr[0][0], pfB0, aB0, 0, 0, 0);
    aB1 = __builtin_amdgcn_mfma_f32_32x32x16_f16(vfr[1][0], pfB0, aB1, 0, 0, 0);
    aA0 = __builtin_amdgcn_mfma_f32_32x32x16_f16(vfr[0][1], pfA1, aA0, 0, 0, 0);
    aA1 = __builtin_amdgcn_mfma_f32_32x32x16_f16(vfr[1][1], pfA1, aA1, 0, 0, 0);
    aB0 = __builtin_amdgcn_mfma_f32_32x32x16_f16(vfr[0][1], pfB1, aB0, 0, 0, 0);
    aB1 = __builtin_amdgcn_mfma_f32_32x32x16_f16(vfr[1][1], pfB1, aB1, 0, 0, 0);
    aA0 = __builtin_amdgcn_mfma_f32_32x32x16_f16(vfr[0][2], pfA2, aA0, 0, 0, 0);
    aA1 = __builtin_amdgcn_mfma_f32_32x32x16_f16(vfr[1][2], pfA2, aA1, 0, 0, 0);
    aB0 = __builtin_amdgcn_mfma_f32_32x32x16_f16(vfr[0][2], pfB2, aB0, 0, 0, 0);
    aB1 = __builtin_amdgcn_mfma_f32_32x32x16_f16(vfr[1][2], pfB2, aB1, 0, 0, 0);
    aA0 = __builtin_amdgcn_mfma_f32_32x32x16_f16(vfr[0][3], pfA3, aA0, 0, 0, 0);
    aA1 = __builtin_amdgcn_mfma_f32_32x32x16_f16(vfr[1][3], pfA3, aA1, 0, 0, 0);
    aB0 = __builtin_amdgcn_mfma_f32_32x32x16_f16(vfr[0][3], pfB3, aB0, 0, 0, 0);
    aB1 = __builtin_amdgcn_mfma_f32_32x32x16_f16(vfr[1][3], pfB3, aB1, 0, 0, 0);
  }
#undef MKPF

  // pair combine: kvh=1 waves deposit partials; kvh=0 waves add and store.
  if (kvh) {
    float* s = &red[qg][l][0];
#pragma unroll
    for (int j = 0; j < 16; ++j) {
      s[j] = aA0[j];
      s[16 + j] = aA1[j];
      s[32 + j] = aB0[j];
      s[48 + j] = aB1[j];
    }
    s[64] = lrowA;
    s[65] = lrowB;
  }
  __syncthreads();
  if (!kvh) {
    const float* s = &red[qg][l][0];
#pragma unroll
    for (int j = 0; j < 16; ++j) {
      aA0[j] += s[j];
      aA1[j] += s[16 + j];
      aB0[j] += s[32 + j];
      aB1[j] += s[48 + j];
    }
    lrowA += s[64];
    lrowB += s[65];

    lrowA += __shfl_xor(lrowA, 32);
    lrowB += __shfl_xor(lrowB, 32);
    float rinvA = 1.0f / lrowA;
    float rinvB = 1.0f / lrowB;
    u16* orowA = att + (size_t)(b * N_ + qb + l31) * C_ + h * D_;
    u16* orowB = orowA + (size_t)32 * C_;
#pragma unroll
    for (int dt = 0; dt < 2; ++dt) {
#pragma unroll
      for (int r2 = 0; r2 < 4; ++r2) {
        int d0 = dt * 32 + r2 * 8 + hi * 4;
        s16x4 hvA, hvB;
#pragma unroll
        for (int i = 0; i < 4; ++i) {
          float vA = (dt ? aA1[r2 * 4 + i] : aA0[r2 * 4 + i]) * rinvA;
          float vB = (dt ? aB1[r2 * 4 + i] : aB0[r2 * 4 + i]) * rinvB;
          hvA[i] = (short)f2h(vA);
          hvB[i] = (short)f2h(vB);
        }
        *(s16x4*)(orowA + d0) = hvA;
        *(s16x4*)(orowB + d0) = hvB;
      }
    }
  }
}

extern "C" void kernel_launch(void* const* d_in, const int* in_sizes, int n_in,
                              void* d_out, int out_size, void* d_ws, size_t ws_size,
                              hipStream_t stream) {
  const float* x = (const float*)d_in[0];
  const float* w_qkv = (const float*)d_in[1];
  const float* b_qkv = (const float*)d_in[2];
  const float* w_proj = (const float*)d_in[3];
  const float* b_proj = (const float*)d_in[4];

  char* ws = (char*)d_ws;
  u16* qkv  = (u16*)(ws + 0);            // 8192*3072*2 = 50331648
  u16* x16  = (u16*)(ws + 50331648);     // 16777216
  u16* wq16 = (u16*)(ws + 67108864);     //  6291456
  u16* wp16 = (u16*)(ws + 73400320);     //  2097152
  u16* kf   = (u16*)(ws + 75497472);     // 16777216  (K fragments)
  u16* vf   = (u16*)(ws + 92274688);     // 16777216  (V fragments)
  u16* att  = (u16*)(ws + 109051904);    // 16777216

  f32_to_f16_all<<<6144, 256, 0, stream>>>(x, w_qkv, w_proj, x16, wq16, wp16);

  gemm_bt<true><<<dim3(64, 24), 256, 0, stream>>>(x16, wq16, b_qkv, qkv, C3);

  kv_prep<<<6144, 256, 0, stream>>>(qkv, kf, vf);

  attn_fused<<<dim3(16, 64), 256, 0, stream>>>(qkv, kf, vf, att);

  gemm_bt<false><<<dim3(64, 8), 256, 0, stream>>>(att, wp16, b_proj, d_out, C_);
}